// Round 5
// baseline (136.838 us; speedup 1.0000x reference)
//
#include <hip/hip_runtime.h>
#include <hip/hip_bf16.h>
#include <math.h>

#define INPUT_DIM 256
#define OUT_DIM   256
#define NDEG      8                    // degree+1
#define KTOT      (INPUT_DIM * NDEG)   // 2048
#define NROWS     (16 * 2048)          // 32768

#define BM  128                        // block rows
#define BK  64                         // 8 inputs * 8 degrees per K-chunk
#define NK  (KTOT / BK)                // 32
#define CHUNK_ELEMS 16384              // full-width B chunk: 256 o * 64 k

typedef __bf16 bf16x8 __attribute__((ext_vector_type(8)));
typedef float  f32x16 __attribute__((ext_vector_type(16)));
typedef float  f32x4  __attribute__((ext_vector_type(4)));

// ---------------------------------------------------------------------------
// Kernel 1: reorder coeffs C[i][o][d] (fp32) -> B pages (bf16).
// R14 mapping change: chunk-local input p = i&7 decomposes as h = p>>2,
// s = p&3 (was s=p>>1, h=p&1). Frag (kc,s,c,ni), lane (l31,h):
//   dst = kc*16384 + (s*4+c)*1024 + ni*512 + h*256 + l31*8 + d
// Both A and B sides use the same permutation -> result identical; the point
// is that lane (l31,h)'s four s-fragments now come from ONE f32x4 x-load
// (inputs 8kc + h*4 + {0..3}).
// ---------------------------------------------------------------------------
__global__ __launch_bounds__(256) void reorder_coeffs(const float* __restrict__ C,
                                                      __bf16* __restrict__ Bt) {
    int g = blockIdx.x * 256 + threadIdx.x;   // 65536 = 256 i * 256 o
    int i = g >> 8;
    int o = g & 255;
    const float4* src = (const float4*)(C + (size_t)i * (OUT_DIM * NDEG) + o * NDEG);
    float4 a = src[0];
    float4 b = src[1];
    bf16x8 v;
    v[0] = (__bf16)a.x; v[1] = (__bf16)a.y; v[2] = (__bf16)a.z; v[3] = (__bf16)a.w;
    v[4] = (__bf16)b.x; v[5] = (__bf16)b.y; v[6] = (__bf16)b.z; v[7] = (__bf16)b.w;
    int kc = i >> 3;
    int p  = i & 7;
    int hh = p >> 2;                   // k-half  (R14: was p&1)
    int s  = p & 3;                    // k-slice (R14: was p>>1)
    int cc = o >> 6;
    int ni = (o >> 5) & 1;
    int l31 = o & 31;
    size_t dst = (size_t)kc * CHUNK_ELEMS + (s * 4 + cc) * 1024 + ni * 512 + hh * 256 + l31 * 8;
    *(bf16x8*)(Bt + dst) = v;   // 16B-aligned
}

// tanh + physicists' Hermite recurrence -> 8 degrees as bf16x8
__device__ __forceinline__ bf16x8 featurize(float xs) {
    float e = __expf(2.0f * xs);            // tanh(x)=1-2/(e^{2x}+1), robust all x
    float t = 1.0f - 2.0f / (e + 1.0f);
    bf16x8 v;
    float hm2 = 1.0f;                       // H_0
    float hm1 = 2.0f * t;                   // H_1
    v[0] = (__bf16)hm2;
    v[1] = (__bf16)hm1;
    #pragma unroll
    for (int d = 2; d < 8; ++d) {
        float h = 2.0f * t * hm1 - 2.0f * (float)(d - 1) * hm2;
        v[d] = (__bf16)h;
        hm2 = hm1; hm1 = h;
    }
    return v;
}

// ---------------------------------------------------------------------------
// Kernel 2 (Round 14): barrier-free direct-featurize.
//  R10-R13 post-mortem: every barrier-cadenced variant keeps MFMA/VALU/LDS
//  ADDITIVE (waves phase-locked by the barrier; 2-block decorrelation is
//  uncontrollable). Root fix: remove the A-LDS exchange entirely. For
//  mfma_32x32x16_bf16, lane (l31,h) holds 8 degrees of ONE input -- exactly
//  featurize()'s output. So each lane featurizes its own A-frag in registers:
//    af_mi(s) = featurize(x[row_mi][8kc + h*4 + s]),  row_mi = mr*64+mi*32+l31
//  Cost: featurize duplicated 4x (c-waves). Gain: NO LDS, NO barriers, no
//  lgkm waits -- waves free-run, VALU+VMEM issue under the matrix pipe
//  (m114). Per-SIMD/chunk: MFMA 1024 cyc vs VALU ~770 + issue ~130.
//  B reg dbuf unchanged; x via f32x4 dbuf (L1-friendly: lanes l/l+32 share a
//  64B line; 2KB/step working set).
// Block 512 thr / 8 waves (2 mr x 4 c), tile 128x256, wave tile 64x64,
// grid 256 = 1 block/CU. VGPR ~176 -> 2 waves/SIMD, no spill.
// ---------------------------------------------------------------------------
__global__ __launch_bounds__(512, 2) void hermite_mfma(const float* __restrict__ x,
                                                       const __bf16* __restrict__ Bt,
                                                       float* __restrict__ out) {
    const int tid  = threadIdx.x;
    const int bm   = blockIdx.x;       // 0..255
    const int wave = tid >> 6;         // 0..7
    const int mr   = wave >> 2;        // 0..1 : row half (64 rows)
    const int c    = wave & 3;         // 0..3 : column slice
    const int lane = tid & 63;
    const int l31  = lane & 31;
    const int h    = lane >> 5;

    // Rows this lane supplies to the A operand (mi = 0/1 sub-blocks).
    const int row0 = bm * BM + mr * 64 + l31;        // mi=0
    const float* xr0 = x + (size_t)row0 * INPUT_DIM + h * 4;
    const float* xr1 = xr0 + (size_t)32 * INPUT_DIM; // mi=1 (+32 rows)

    // B pages for column slice c: frag(kc,s,ni) at Bt + kc*16384 + (s*4+c)*1024
    //   + ni*512 + lane*8   (lane*8 = h*256 + l31*8)
    const __bf16* bbase = Bt + (size_t)c * 1024 + lane * 8;

    f32x16 acc[2][2] = {};
    bf16x8 bfr0[4][2];                 // chunk B-frag buffer A (static names)
    bf16x8 bfr1[4][2];                 // chunk B-frag buffer B

#define BLOAD(DST, KC)                                                       \
    {                                                                        \
        const __bf16* g = bbase + (size_t)(KC) * CHUNK_ELEMS;                \
        _Pragma("unroll")                                                    \
        for (int s = 0; s < 4; ++s) {                                        \
            DST[s][0] = *(const bf16x8*)(g + s * 4096);                      \
            DST[s][1] = *(const bf16x8*)(g + s * 4096 + 512);                \
        }                                                                    \
    }

    // ---- prologue: chunk 0 B + x ----
    f32x4 xa0 = *(const f32x4*)(xr0);
    f32x4 xa1 = *(const f32x4*)(xr1);
    BLOAD(bfr0, 0);
    f32x4 xb0 = xa0, xb1 = xa1;        // init to silence uninitialized use

    // One chunk: prefetch next chunk's B + x, then 4 s-slices of
    // {featurize A-frags in regs, 4 MFMAs}. No barriers, no LDS.
#define STEP(KC, CUR, NXT, XC0, XC1, XN0, XN1)                               \
    {                                                                        \
        if ((KC) + 1 < NK) {                                                 \
            BLOAD(NXT, (KC) + 1);                                            \
            XN0 = *(const f32x4*)(xr0 + ((KC) + 1) * 8);                     \
            XN1 = *(const f32x4*)(xr1 + ((KC) + 1) * 8);                     \
        }                                                                    \
        _Pragma("unroll")                                                    \
        for (int s = 0; s < 4; ++s) {                                        \
            bf16x8 af0 = featurize(XC0[s]);                                  \
            bf16x8 af1 = featurize(XC1[s]);                                  \
            acc[0][0] = __builtin_amdgcn_mfma_f32_32x32x16_bf16(af0, CUR[s][0], acc[0][0], 0, 0, 0); \
            acc[0][1] = __builtin_amdgcn_mfma_f32_32x32x16_bf16(af0, CUR[s][1], acc[0][1], 0, 0, 0); \
            acc[1][0] = __builtin_amdgcn_mfma_f32_32x32x16_bf16(af1, CUR[s][0], acc[1][0], 0, 0, 0); \
            acc[1][1] = __builtin_amdgcn_mfma_f32_32x32x16_bf16(af1, CUR[s][1], acc[1][1], 0, 0, 0); \
        }                                                                    \
    }

    for (int kc2 = 0; kc2 < NK; kc2 += 2) {
        STEP(kc2,     bfr0, bfr1, xa0, xa1, xb0, xb1);
        STEP(kc2 + 1, bfr1, bfr0, xb0, xb1, xa0, xa1);
    }
#undef STEP
#undef BLOAD

    // ---- epilogue: 32x32 C/D col=lane&31, row=(reg&3)+8*(reg>>2)+4*h (R7-validated) ----
    #pragma unroll
    for (int mi = 0; mi < 2; ++mi)
        #pragma unroll
        for (int ni = 0; ni < 2; ++ni) {
            #pragma unroll
            for (int r = 0; r < 16; ++r) {
                int rl  = (r & 3) + 8 * (r >> 2) + 4 * h;
                int row = bm * BM + mr * 64 + mi * 32 + rl;
                out[(size_t)row * OUT_DIM + c * 64 + ni * 32 + l31] = acc[mi][ni][r];
            }
        }
}

// ---------------------------------------------------------------------------
extern "C" void kernel_launch(void* const* d_in, const int* in_sizes, int n_in,
                              void* d_out, int out_size, void* d_ws, size_t ws_size,
                              hipStream_t stream) {
    const float* x = (const float*)d_in[0];          // [16,2048,256] fp32
    const float* C = (const float*)d_in[1];          // [256,256,8]  fp32
    float* out = (float*)d_out;                      // [16,2048,256] fp32
    __bf16* Bt = (__bf16*)d_ws;                      // paged [32][16384] bf16, 1 MB

    reorder_coeffs<<<dim3((INPUT_DIM * OUT_DIM) / 256), dim3(256), 0, stream>>>(C, Bt);
    hermite_mfma<<<dim3(NROWS / BM), dim3(512), 0, stream>>>(x, Bt, out);
}

// Round 6
// 117.005 us; speedup vs baseline: 1.1695x; 1.1695x over previous
//
#include <hip/hip_runtime.h>
#include <hip/hip_bf16.h>
#include <math.h>

#define INPUT_DIM 256
#define OUT_DIM   256
#define NDEG      8                    // degree+1
#define KTOT      (INPUT_DIM * NDEG)   // 2048
#define NROWS     (16 * 2048)          // 32768

#define BM  128                        // block rows (featurize exactly once globally)
#define BK  64                         // 8 inputs * 8 degrees per K-chunk
#define NK  (KTOT / BK)                // 32
#define SUPER 4                        // chunks per super-step (barrier granularity)
#define NSUP  (NK / SUPER)             // 8
#define CHUNK_ELEMS 16384              // full-width B chunk: 256 o * 64 k

typedef __bf16 bf16x8 __attribute__((ext_vector_type(8)));
typedef float  f32x16 __attribute__((ext_vector_type(16)));

// ---------------------------------------------------------------------------
// Kernel 1: reorder coeffs C[i][o][d] (fp32) -> B pages (bf16). R11 layout:
// chunk-local input p = i&7 -> s = p>>1, h = p&1 (pairs with A page index
// 2*s+h in the GEMM). Frag (kc,s,c,ni), lane (l31,h):
//   dst = kc*16384 + (s*4+c)*1024 + ni*512 + h*256 + l31*8 + d
// ---------------------------------------------------------------------------
__global__ __launch_bounds__(256) void reorder_coeffs(const float* __restrict__ C,
                                                      __bf16* __restrict__ Bt) {
    int g = blockIdx.x * 256 + threadIdx.x;   // 65536 = 256 i * 256 o
    int i = g >> 8;
    int o = g & 255;
    const float4* src = (const float4*)(C + (size_t)i * (OUT_DIM * NDEG) + o * NDEG);
    float4 a = src[0];
    float4 b = src[1];
    bf16x8 v;
    v[0] = (__bf16)a.x; v[1] = (__bf16)a.y; v[2] = (__bf16)a.z; v[3] = (__bf16)a.w;
    v[4] = (__bf16)b.x; v[5] = (__bf16)b.y; v[6] = (__bf16)b.z; v[7] = (__bf16)b.w;
    int kc = i >> 3;
    int p  = i & 7;
    int s  = p >> 1;
    int hh = p & 1;
    int cc = o >> 6;
    int ni = (o >> 5) & 1;
    int l31 = o & 31;
    size_t dst = (size_t)kc * CHUNK_ELEMS + (s * 4 + cc) * 1024 + ni * 512 + hh * 256 + l31 * 8;
    *(bf16x8*)(Bt + dst) = v;   // 16B-aligned
}

// tanh + physicists' Hermite recurrence -> 8 degrees as bf16x8
__device__ __forceinline__ bf16x8 featurize(float xs) {
    float e = __expf(2.0f * xs);            // tanh(x)=1-2/(e^{2x}+1), robust all x
    float t = 1.0f - 2.0f / (e + 1.0f);
    bf16x8 v;
    float hm2 = 1.0f;                       // H_0
    float hm1 = 2.0f * t;                   // H_1
    v[0] = (__bf16)hm2;
    v[1] = (__bf16)hm1;
    #pragma unroll
    for (int d = 2; d < 8; ++d) {
        float h = 2.0f * t * hm1 - 2.0f * (float)(d - 1) * hm2;
        v[d] = (__bf16)h;
        hm2 = hm1; hm1 = h;
    }
    return v;
}

// lgkm-only barrier: each wave's own LDS writes/reads complete (lgkmcnt(0))
// before it signals -- full producer/consumer requirement for the Alds dbuf.
// B/x prefetch loads target registers and carry compiler vmcnt waits at use
// sites; they legally stay in flight across the barrier.
#define BARRIER() do {                                             \
    asm volatile("s_waitcnt lgkmcnt(0)" ::: "memory");             \
    __builtin_amdgcn_s_barrier();                                  \
    asm volatile("" ::: "memory");                                 \
} while (0)

// ---------------------------------------------------------------------------
// Kernel 2 (Round 15): R11 base + wave phase-stagger + setprio.
//  R11-R14 post-mortem: R11 (44.9us) loses because all 8 waves march through
//  identical code in lockstep from each barrier -- everyone featurizes at
//  the same time (matrix idle) then everyone MFMAs (VALU idle): pipes add
//  (13.5k cyc/super = MFMA 4.1k + VALU 3.3k + LDS/stalls). R14 (dup x4
//  featurize, no LDS) was VALU-issue-bound at 70us -- featurize must stay
//  exactly-once. Fix here: EVEN waves run [F x8][C0..C3], ODD waves run
//  [C0 C1][F x8][C2 C3] -- half the waves in VALU phase while the other
//  half feeds the matrix pipe. Legal: B-frags are per-wave regs; A-LDS is
//  super-granular (any within-super order; writes land before the single
//  end-barrier; barrier counts identical on both paths). s_setprio(1)
//  around MFMA clusters (T5) now has role diversity to arbitrate.
// Block 512 thr / 8 waves (2 mr x 4 c), tile 128x256, wave tile 64x64,
// grid 256 = 1 block/CU. Matrix floor 4096 cyc/CU/super = 13.7us total.
// ---------------------------------------------------------------------------
__global__ __launch_bounds__(512, 2) void hermite_mfma(const float* __restrict__ x,
                                                       const __bf16* __restrict__ Bt,
                                                       float* __restrict__ out) {
    // [buf][chunk-in-super cc*8192 + page j*1024 + m*8]; page = input (cc,j)
    __shared__ __align__(16) __bf16 Alds[2][SUPER * 8192];   // 128 KB

    const int tid  = threadIdx.x;
    const int bm   = blockIdx.x;       // 0..255
    const int wave = tid >> 6;         // 0..7
    const int mr   = wave >> 2;        // 0..1 : row half
    const int c    = wave & 3;         // 0..3 : column slice
    const int lane = tid & 63;
    const int l31  = lane & 31;
    const int h    = lane >> 5;

    // Featurize mapping: thread (m, pg) covers row m, chunk-in-super pg,
    // inputs sup*32 + pg*8 + j (j=0..7). Exactly-once globally.
    const int m  = tid & 127;
    const int pg = tid >> 7;           // 0..3
    const float* xptr = x + (size_t)(bm * BM + m) * INPUT_DIM + pg * 8;

    // B pages for column slice c: frag(kc,s,ni) at Bt + kc*16384 + (s*4+c)*1024
    //   + ni*512 + lane*8
    const __bf16* bbase = Bt + (size_t)c * 1024 + lane * 8;

    f32x16 acc[2][2] = {};
    bf16x8 bfr0[4][2];                 // chunk B-frag buffer A (static names)
    bf16x8 bfr1[4][2];                 // chunk B-frag buffer B

#define BLOAD(DST, KC)                                                       \
    if ((KC) < NK) {                                                         \
        const __bf16* g = bbase + (size_t)(KC) * CHUNK_ELEMS;                \
        _Pragma("unroll")                                                    \
        for (int s = 0; s < 4; ++s) {                                        \
            DST[s][0] = *(const bf16x8*)(g + s * 4096);                      \
            DST[s][1] = *(const bf16x8*)(g + s * 4096 + 512);                \
        }                                                                    \
    }

#define FEATW(NB, J, XS)                                                     \
    *(bf16x8*)(&Alds[NB][pg * 8192 + (J) * 1024 + m * 8]) = featurize(XS)

#define CHUNK_COMPUTE(CB, CC, CUR)                                           \
    {                                                                        \
        __builtin_amdgcn_s_setprio(1);                                       \
        _Pragma("unroll")                                                    \
        for (int s4 = 0; s4 < 4; ++s4) {                                     \
            bf16x8 af0 = *(const bf16x8*)(&Alds[CB][(CC) * 8192 + (2 * s4 + h) * 1024 + mr * 512 + l31 * 8]);       \
            bf16x8 af1 = *(const bf16x8*)(&Alds[CB][(CC) * 8192 + (2 * s4 + h) * 1024 + mr * 512 + 256 + l31 * 8]); \
            acc[0][0] = __builtin_amdgcn_mfma_f32_32x32x16_bf16(af0, CUR[s4][0], acc[0][0], 0, 0, 0); \
            acc[0][1] = __builtin_amdgcn_mfma_f32_32x32x16_bf16(af0, CUR[s4][1], acc[0][1], 0, 0, 0); \
            acc[1][0] = __builtin_amdgcn_mfma_f32_32x32x16_bf16(af1, CUR[s4][0], acc[1][0], 0, 0, 0); \
            acc[1][1] = __builtin_amdgcn_mfma_f32_32x32x16_bf16(af1, CUR[s4][1], acc[1][1], 0, 0, 0); \
        }                                                                    \
        __builtin_amdgcn_s_setprio(0);                                       \
    }

    // ---- prologue: featurize super 0 into buf 0, B chunk 0, x for super 1 ----
    float4 xq0 = *(const float4*)(xptr);
    float4 xq1 = *(const float4*)(xptr + 4);
    BLOAD(bfr0, 0);
    float4 xa0 = *(const float4*)(xptr + 32);
    float4 xa1 = *(const float4*)(xptr + 36);
    float4 xb0 = xa0, xb1 = xa1;       // init to silence uninitialized use
    FEATW(0, 0, xq0.x); FEATW(0, 1, xq0.y); FEATW(0, 2, xq0.z); FEATW(0, 3, xq0.w);
    FEATW(0, 4, xq1.x); FEATW(0, 5, xq1.y); FEATW(0, 6, xq1.z); FEATW(0, 7, xq1.w);
    BARRIER();

    // EVEN waves: featurize first, then the 4 chunk-computes.
#define SUPER_STEP_E(S, CB, NB, XC0, XC1, XN0, XN1)                          \
    {                                                                        \
        const bool dofeat = (S) + 1 < NSUP;                                  \
        if (dofeat) { FEATW(NB, 0, XC0.x); FEATW(NB, 1, XC0.y);              \
                      FEATW(NB, 2, XC0.z); FEATW(NB, 3, XC0.w); }            \
        BLOAD(bfr1, (S) * 4 + 1);                                            \
        if (dofeat) { FEATW(NB, 4, XC1.x); FEATW(NB, 5, XC1.y);              \
                      FEATW(NB, 6, XC1.z); FEATW(NB, 7, XC1.w); }            \
        CHUNK_COMPUTE(CB, 0, bfr0);                                          \
        BLOAD(bfr0, (S) * 4 + 2);                                            \
        CHUNK_COMPUTE(CB, 1, bfr1);                                          \
        BLOAD(bfr1, (S) * 4 + 3);                                            \
        CHUNK_COMPUTE(CB, 2, bfr0);                                          \
        BLOAD(bfr0, (S) * 4 + 4);                                            \
        if ((S) + 2 < NSUP) {                                                \
            XN0 = *(const float4*)(xptr + ((S) + 2) * 32);                   \
            XN1 = *(const float4*)(xptr + ((S) + 2) * 32 + 4);               \
        }                                                                    \
        CHUNK_COMPUTE(CB, 3, bfr1);                                          \
        BARRIER();                                                           \
    }

    // ODD waves: chunks 0-1 first (B frags prefetched last super), featurize
    // in the middle, chunks 2-3 last. Complements the even schedule in time.
#define SUPER_STEP_O(S, CB, NB, XC0, XC1, XN0, XN1)                          \
    {                                                                        \
        const bool dofeat = (S) + 1 < NSUP;                                  \
        BLOAD(bfr1, (S) * 4 + 1);                                            \
        CHUNK_COMPUTE(CB, 0, bfr0);                                          \
        BLOAD(bfr0, (S) * 4 + 2);                                            \
        CHUNK_COMPUTE(CB, 1, bfr1);                                          \
        if (dofeat) { FEATW(NB, 0, XC0.x); FEATW(NB, 1, XC0.y);              \
                      FEATW(NB, 2, XC0.z); FEATW(NB, 3, XC0.w);              \
                      FEATW(NB, 4, XC1.x); FEATW(NB, 5, XC1.y);              \
                      FEATW(NB, 6, XC1.z); FEATW(NB, 7, XC1.w); }            \
        BLOAD(bfr1, (S) * 4 + 3);                                            \
        CHUNK_COMPUTE(CB, 2, bfr0);                                          \
        if ((S) + 2 < NSUP) {                                                \
            XN0 = *(const float4*)(xptr + ((S) + 2) * 32);                   \
            XN1 = *(const float4*)(xptr + ((S) + 2) * 32 + 4);               \
        }                                                                    \
        BLOAD(bfr0, (S) * 4 + 4);                                            \
        CHUNK_COMPUTE(CB, 3, bfr1);                                          \
        BARRIER();                                                           \
    }

    if ((wave & 1) == 0) {
        for (int sp = 0; sp < NSUP; sp += 2) {
            SUPER_STEP_E(sp,     0, 1, xa0, xa1, xb0, xb1);
            SUPER_STEP_E(sp + 1, 1, 0, xb0, xb1, xa0, xa1);
        }
    } else {
        for (int sp = 0; sp < NSUP; sp += 2) {
            SUPER_STEP_O(sp,     0, 1, xa0, xa1, xb0, xb1);
            SUPER_STEP_O(sp + 1, 1, 0, xb0, xb1, xa0, xa1);
        }
    }
#undef SUPER_STEP_E
#undef SUPER_STEP_O
#undef CHUNK_COMPUTE
#undef FEATW
#undef BLOAD

    // ---- epilogue: 32x32 C/D col=lane&31, row=(reg&3)+8*(reg>>2)+4*h (R7-validated) ----
    #pragma unroll
    for (int mi = 0; mi < 2; ++mi)
        #pragma unroll
        for (int ni = 0; ni < 2; ++ni) {
            #pragma unroll
            for (int r = 0; r < 16; ++r) {
                int rl  = (r & 3) + 8 * (r >> 2) + 4 * h;
                int row = bm * BM + mr * 64 + mi * 32 + rl;
                out[(size_t)row * OUT_DIM + c * 64 + ni * 32 + l31] = acc[mi][ni][r];
            }
        }
}

// ---------------------------------------------------------------------------
extern "C" void kernel_launch(void* const* d_in, const int* in_sizes, int n_in,
                              void* d_out, int out_size, void* d_ws, size_t ws_size,
                              hipStream_t stream) {
    const float* x = (const float*)d_in[0];          // [16,2048,256] fp32
    const float* C = (const float*)d_in[1];          // [256,256,8]  fp32
    float* out = (float*)d_out;                      // [16,2048,256] fp32
    __bf16* Bt = (__bf16*)d_ws;                      // paged [32][16384] bf16, 1 MB

    reorder_coeffs<<<dim3((INPUT_DIM * OUT_DIM) / 256), dim3(256), 0, stream>>>(C, Bt);
    hermite_mfma<<<dim3(NROWS / BM), dim3(512), 0, stream>>>(x, Bt, out);
}